// Round 4
// baseline (205.486 us; speedup 1.0000x reference)
//
#include <hip/hip_runtime.h>

// YOLO loss: input [B,30,7,7] f32, target [B,7,7,30] f32 -> scalar f32.
//
// Round 4: rounds 2-3 showed the compiler's register-pressure-minimizing
// scheduler sinks each load to just before its use (VGPR_Count stayed 40
// despite a 128 budget) -> ~1 load in flight per wave -> latency-bound at
// 1.5 TB/s. Fix: __builtin_amdgcn_sched_barrier(0) between the 45-load
// block and the first consumer. Nothing may be scheduled across it, so all
// loads issue back-to-back and their results stay live (~45 outstanding
// loads/wave = 15 KB, far past the BW-latency product).

#define NCH   30
#define CELLS 49
#define TPB   256
#define IMGSZ 448.0f
#define CELLSZ 64.0f

__device__ __forceinline__ float iou_f(float ax1, float ay1, float ax2, float ay2,
                                       float bx1, float by1, float bx2, float by2) {
    float l  = fmaxf(ax1, bx1);
    float r  = fminf(ax2, bx2);
    float t  = fmaxf(ay1, by1);
    float bo = fminf(ay2, by2);
    bool  m  = (l < r) && (t < bo);
    float inter = (r - l) * (bo - t);
    float uni   = (ax2 - ax1) * (ay2 - ay1) + (bx2 - bx1) * (by2 - by1);
    float denom = uni - inter;
    return m ? (inter / denom) : 0.0f;
}

__device__ __forceinline__ void decode_box(float p0, float p1, float p2, float p3,
                                           float gx, float gy,
                                           float& x1, float& y1, float& x2, float& y2) {
    float cx = p0 * CELLSZ + gx;
    float cy = p1 * CELLSZ + gy;
    float w  = p2 * IMGSZ;
    float h  = p3 * IMGSZ;
    x1 = fminf(fmaxf(cx - w * 0.5f, 0.0f), IMGSZ);
    y1 = fminf(fmaxf(cy - h * 0.5f, 0.0f), IMGSZ);
    x2 = fminf(fmaxf(cx + w * 0.5f, 0.0f), IMGSZ);
    y2 = fminf(fmaxf(cy + h * 0.5f, 0.0f), IMGSZ);
}

// cap 128 VGPR/wave (4 waves/EU) so the pinned 45-load batch fits without spill
__global__ __launch_bounds__(TPB, 4) void yolo_loss_kernel(
        const float* __restrict__ input,   // [B,30,7,7]
        const float* __restrict__ target,  // [B,7,7,30] == [N,30]
        float* __restrict__ out,
        int ncells) {
    __shared__ float red[TPB / 64];

    const int tid = threadIdx.x;
    const int n   = blockIdx.x * TPB + tid;

    float loss = 0.0f;
    if (n < ncells) {
        const int b    = n / CELLS;
        const int cell = n - b * CELLS;

        const float2* __restrict__ tp =
            reinterpret_cast<const float2*>(target) + (long long)n * 15;
        const float* __restrict__ ip = input + b * (NCH * CELLS) + cell;

        // ---- issue ALL 45 loads; sched_barrier forbids sinking them ----
        float2 tv[15];
        float  x[NCH];
        #pragma unroll
        for (int k = 0; k < 15; ++k) tv[k] = tp[k];
        #pragma unroll
        for (int c = 0; c < NCH; ++c) x[c] = ip[c * CELLS];

        __builtin_amdgcn_sched_barrier(0);   // nothing moves across: all loads in flight here

        float tl[NCH];
        #pragma unroll
        for (int k = 0; k < 15; ++k) { tl[2 * k] = tv[k].x; tl[2 * k + 1] = tv[k].y; }

        const int row  = cell / 7;
        const int col  = cell - row * 7;
        const float gx = (float)col * CELLSZ;
        const float gy = (float)row * CELLSZ;

        float p0x1, p0y1, p0x2, p0y2, p1x1, p1y1, p1x2, p1y2;
        decode_box(x[0], x[1], x[2], x[3], gx, gy, p0x1, p0y1, p0x2, p0y2);
        decode_box(x[5], x[6], x[7], x[8], gx, gy, p1x1, p1y1, p1x2, p1y2);
        float t0x1, t0y1, t0x2, t0y2, t1x1, t1y1, t1x2, t1y2;
        decode_box(tl[0], tl[1], tl[2], tl[3], gx, gy, t0x1, t0y1, t0x2, t0y2);
        decode_box(tl[5], tl[6], tl[7], tl[8], gx, gy, t1x1, t1y1, t1x2, t1y2);

        float iou1 = iou_f(p0x1, p0y1, p0x2, p0y2, t0x1, t0y1, t0x2, t0y2);
        float iou2 = iou_f(p1x1, p1y1, p1x2, p1y2, t1x1, t1y1, t1x2, t1y2);

        bool  mask = iou1 < iou2;
        float iou  = mask ? iou2 : iou1;
        float s0 = mask ? x[5] : x[0];
        float s1 = mask ? x[6] : x[1];
        float s2 = mask ? x[7] : x[2];
        float s3 = mask ? x[8] : x[3];
        float s4 = mask ? x[9] : x[4];

        float w = (tl[4] == 1.0f) ? 1.0f : 0.0f;

        float d0 = s0 - tl[0];
        float d1 = s1 - tl[1];
        float coord = d0 * d0 + d1 * d1;

        float ds2 = sqrtf(s2) - sqrtf(tl[2]);
        float ds3 = sqrtf(s3) - sqrtf(tl[3]);
        float size = ds2 * ds2 + ds3 * ds3;

        float dc = s4 - iou;
        float conf = dc * dc;
        float noobj = s4 * s4;

        float cls = 0.0f;
        #pragma unroll
        for (int c = 10; c < NCH; ++c) {
            float d = x[c] - tl[c];
            cls += d * d;
        }

        loss = w * (5.0f * (coord + size) + conf + cls) + 0.5f * (1.0f - w) * noobj;
    }

    // Wave reduce (64 lanes), then block reduce, one atomic per block.
    #pragma unroll
    for (int off = 32; off > 0; off >>= 1)
        loss += __shfl_down(loss, off, 64);

    const int wid  = tid >> 6;
    const int lane = tid & 63;
    if (lane == 0) red[wid] = loss;
    __syncthreads();
    if (tid == 0) {
        float s = 0.0f;
        #pragma unroll
        for (int i = 0; i < TPB / 64; ++i) s += red[i];
        atomicAdd(out, s);
    }
}

extern "C" void kernel_launch(void* const* d_in, const int* in_sizes, int n_in,
                              void* d_out, int out_size, void* d_ws, size_t ws_size,
                              hipStream_t stream) {
    const float* input  = (const float*)d_in[0];   // [B,30,7,7]
    const float* target = (const float*)d_in[1];   // [B,7,7,30]
    float* out = (float*)d_out;

    const int ncells = in_sizes[0] / NCH;          // B*49 = 802816
    const int blocks = (ncells + TPB - 1) / TPB;   // 3136

    // d_out is poisoned 0xAA before every timed launch -> zero it (capture-safe).
    hipMemsetAsync(d_out, 0, sizeof(float), stream);
    yolo_loss_kernel<<<blocks, TPB, 0, stream>>>(input, target, out, ncells);
}